// Round 1
// baseline (704.397 us; speedup 1.0000x reference)
//
#include <hip/hip_runtime.h>

#define NPTS 8192
#define SPTS 2048
#define BATCH 4
#define CO 256

// ---------------- transpose W [O,K] -> WT [K,O] ----------------
__global__ void transpose_w(const float* __restrict__ W, float* __restrict__ WT,
                            int O, int K) {
  int idx = blockIdx.x * 256 + threadIdx.x;
  if (idx < O * K) {
    int o = idx / K, k = idx - o * K;
    WT[(size_t)k * O + o] = W[idx];
  }
}

// ---------------- KNN (k=3) + inverse-distance-weighted interpolation ----------------
// One thread per query point. xyz2 (+ precomputed |p|^2) staged in LDS as float4.
// Distance formula replicates the reference exactly in f32 (no fma contraction):
//   d = (a2 + b2) - 2*((x1x2 + y1y2) + z1z2)
// Stable strict-< insertion == lax.top_k lowest-index tie-break.
__global__ __launch_bounds__(128) void knn_interp(
    const float* __restrict__ xyz1, const float* __restrict__ xyz2,
    const float* __restrict__ points2, float* __restrict__ interp) {
  __shared__ float4 spt[SPTS];
  const int b = blockIdx.y;
  const int t = threadIdx.x;
  #pragma unroll
  for (int i = 0; i < SPTS / 128; ++i) {
    int s = t + i * 128;
    const float* p = xyz2 + ((size_t)b * SPTS + s) * 3;
    float x = p[0], y = p[1], z = p[2];
    float b2 = __fadd_rn(__fadd_rn(__fmul_rn(x, x), __fmul_rn(y, y)), __fmul_rn(z, z));
    spt[s] = make_float4(x, y, z, b2);
  }
  __syncthreads();

  const int n = blockIdx.x * 128 + t;
  const float* q = xyz1 + ((size_t)b * NPTS + n) * 3;
  float qx = q[0], qy = q[1], qz = q[2];
  float a2 = __fadd_rn(__fadd_rn(__fmul_rn(qx, qx), __fmul_rn(qy, qy)), __fmul_rn(qz, qz));

  float d0 = 1e30f, d1 = 1e30f, d2 = 1e30f;
  int i0 = 0, i1 = 0, i2 = 0;
  #pragma unroll 4
  for (int s = 0; s < SPTS; ++s) {
    float4 p = spt[s];
    float dot = __fadd_rn(__fadd_rn(__fmul_rn(qx, p.x), __fmul_rn(qy, p.y)), __fmul_rn(qz, p.z));
    float d = __fsub_rn(__fadd_rn(a2, p.w), __fmul_rn(2.0f, dot));
    if (d < d2) {
      if (d < d1) {
        d2 = d1; i2 = i1;
        if (d < d0) { d1 = d0; i1 = i0; d0 = d; i0 = s; }
        else        { d1 = d;  i1 = s; }
      } else { d2 = d; i2 = s; }
    }
  }

  float r0 = 1.0f / __fadd_rn(d0, 1e-8f);
  float r1 = 1.0f / __fadd_rn(d1, 1e-8f);
  float r2 = 1.0f / __fadd_rn(d2, 1e-8f);
  float rs = __fadd_rn(__fadd_rn(r0, r1), r2);
  float w0 = r0 / rs, w1 = r1 / rs, w2 = r2 / rs;

  const float* p2 = points2 + (size_t)b * CO * SPTS;
  float* op = interp + (size_t)b * CO * NPTS + n;
  #pragma unroll 4
  for (int c = 0; c < CO; ++c) {
    const float* row = p2 + (size_t)c * SPTS;
    float v = __fadd_rn(__fadd_rn(__fmul_rn(row[i0], w0), __fmul_rn(row[i1], w1)),
                        __fmul_rn(row[i2], w2));
    op[(size_t)c * NPTS] = v;
  }
}

// ---------------- fp32 GEMM: Z[b,o,n] = sum_k WT[k,o] * X[b,k,n] + bias[o] ----------------
// Tile: 256 o x 64 n x 32 k. 256 threads, 8x8 micro-tile each.
// X split across two source tensors at k=ksplit (stage 1: points1 | interp).
// Fused per-channel sum / sumsq (post-bias) for BatchNorm via shfl_xor + atomics.
__global__ __launch_bounds__(256) void gemm_stats(
    const float* __restrict__ WT, const float* __restrict__ Xa,
    const float* __restrict__ Xb, const float* __restrict__ bias,
    float* __restrict__ Z, float* __restrict__ stats, int K, int ksplit) {
  __shared__ __align__(16) float As[32][256];
  __shared__ __align__(16) float Bs[32][64];
  const int t = threadIdx.x;
  const int b = blockIdx.z;
  const int nBase = blockIdx.x * 64;
  const int to = t >> 3;   // 0..31 -> o = to*8..to*8+7
  const int tn = t & 7;    // 0..7  -> n = nBase + tn*8..+7
  const int cb = K - ksplit;

  float acc[8][8];
  #pragma unroll
  for (int i = 0; i < 8; ++i)
    #pragma unroll
    for (int j = 0; j < 8; ++j) acc[i][j] = 0.f;

  for (int k0 = 0; k0 < K; k0 += 32) {
    // stage A: 32x256 floats (2048 float4), linear LDS writes
    #pragma unroll
    for (int i = 0; i < 8; ++i) {
      int e = t + i * 256;
      int row = e >> 6, c4 = e & 63;
      float4 v = *reinterpret_cast<const float4*>(WT + (size_t)(k0 + row) * 256 + c4 * 4);
      reinterpret_cast<float4*>(&As[0][0])[e] = v;
    }
    // stage B: 32x64 floats (512 float4)
    #pragma unroll
    for (int i = 0; i < 2; ++i) {
      int e = t + i * 256;
      int row = e >> 4, c4 = e & 15;
      int k = k0 + row;
      const float* src = (k < ksplit)
          ? (Xa + ((size_t)b * ksplit + k) * NPTS)
          : (Xb + ((size_t)b * cb + (k - ksplit)) * NPTS);
      float4 v = *reinterpret_cast<const float4*>(src + nBase + c4 * 4);
      reinterpret_cast<float4*>(&Bs[0][0])[e] = v;
    }
    __syncthreads();
    #pragma unroll
    for (int kk = 0; kk < 32; ++kk) {
      float a[8], bb[8];
      *reinterpret_cast<float4*>(&a[0]) = *reinterpret_cast<const float4*>(&As[kk][to * 8]);
      *reinterpret_cast<float4*>(&a[4]) = *reinterpret_cast<const float4*>(&As[kk][to * 8 + 4]);
      *reinterpret_cast<float4*>(&bb[0]) = *reinterpret_cast<const float4*>(&Bs[kk][tn * 8]);
      *reinterpret_cast<float4*>(&bb[4]) = *reinterpret_cast<const float4*>(&Bs[kk][tn * 8 + 4]);
      #pragma unroll
      for (int i = 0; i < 8; ++i)
        #pragma unroll
        for (int j = 0; j < 8; ++j)
          acc[i][j] = fmaf(a[i], bb[j], acc[i][j]);
    }
    __syncthreads();
  }

  // epilogue: +bias, store, per-channel partial stats
  float s1[8], s2[8];
  #pragma unroll
  for (int i = 0; i < 8; ++i) {
    int o = to * 8 + i;
    float bv = bias[o];
    float ls = 0.f, lq = 0.f;
    #pragma unroll
    for (int j = 0; j < 8; ++j) {
      float v = acc[i][j] + bv;
      acc[i][j] = v;
      ls += v; lq += v * v;
    }
    s1[i] = ls; s2[i] = lq;
    size_t base = ((size_t)b * CO + o) * NPTS + nBase + tn * 8;
    *reinterpret_cast<float4*>(Z + base) =
        make_float4(acc[i][0], acc[i][1], acc[i][2], acc[i][3]);
    *reinterpret_cast<float4*>(Z + base + 4) =
        make_float4(acc[i][4], acc[i][5], acc[i][6], acc[i][7]);
  }
  // reduce over the 8 tn lanes (same to-group lives in one wave)
  #pragma unroll
  for (int m = 4; m >= 1; m >>= 1) {
    #pragma unroll
    for (int i = 0; i < 8; ++i) {
      s1[i] += __shfl_xor(s1[i], m);
      s2[i] += __shfl_xor(s2[i], m);
    }
  }
  if (tn == 0) {
    #pragma unroll
    for (int i = 0; i < 8; ++i) {
      int o = to * 8 + i;
      atomicAdd(stats + o, s1[i]);
      atomicAdd(stats + CO + o, s2[i]);
    }
  }
}

// ---------------- BN finalize: stats -> per-channel scale/shift ----------------
__global__ void finalize_bn(const float* __restrict__ stats,
                            const float* __restrict__ gamma,
                            const float* __restrict__ beta,
                            float* __restrict__ ss) {
  int c = threadIdx.x;
  const float inv = 1.0f / 32768.0f;
  float mean = stats[c] * inv;
  float var = stats[256 + c] * inv - mean * mean;
  float sc = gamma[c] * rsqrtf(var + 1e-5f);
  ss[c] = sc;
  ss[256 + c] = beta[c] - mean * sc;
}

// ---------------- elementwise BN (+ReLU) ----------------
__global__ __launch_bounds__(256) void bn_act(const float* __restrict__ Z,
                                              const float* __restrict__ ss,
                                              float* __restrict__ Y, int relu) {
  size_t i4 = (size_t)blockIdx.x * 256 + threadIdx.x;  // float4 index
  int o = (int)((i4 >> 11) & 255);
  float sc = ss[o], sh = ss[256 + o];
  float4 z = reinterpret_cast<const float4*>(Z)[i4];
  float4 y;
  y.x = sc * z.x + sh; y.y = sc * z.y + sh; y.z = sc * z.z + sh; y.w = sc * z.w + sh;
  if (relu) {
    y.x = fmaxf(y.x, 0.f); y.y = fmaxf(y.y, 0.f);
    y.z = fmaxf(y.z, 0.f); y.w = fmaxf(y.w, 0.f);
  }
  reinterpret_cast<float4*>(Y)[i4] = y;
}

// ---------------- final: BN(no relu) + residual + ReLU, in-place on out ----------------
__global__ __launch_bounds__(256) void bn_res(const float* __restrict__ Z,
                                              const float* __restrict__ ss,
                                              float* __restrict__ out) {
  size_t i4 = (size_t)blockIdx.x * 256 + threadIdx.x;
  int o = (int)((i4 >> 11) & 255);
  float sc = ss[o], sh = ss[256 + o];
  float4 z = reinterpret_cast<const float4*>(Z)[i4];
  float4 x = reinterpret_cast<const float4*>(out)[i4];
  float4 y;
  y.x = fmaxf(sc * z.x + sh + x.x, 0.f);
  y.y = fmaxf(sc * z.y + sh + x.y, 0.f);
  y.z = fmaxf(sc * z.z + sh + x.z, 0.f);
  y.w = fmaxf(sc * z.w + sh + x.w, 0.f);
  reinterpret_cast<float4*>(out)[i4] = y;
}

extern "C" void kernel_launch(void* const* d_in, const int* in_sizes, int n_in,
                              void* d_out, int out_size, void* d_ws, size_t ws_size,
                              hipStream_t stream) {
  const float* xyz1   = (const float*)d_in[0];
  const float* xyz2   = (const float*)d_in[1];
  const float* points1= (const float*)d_in[2];
  const float* points2= (const float*)d_in[3];
  const float* fuse_w = (const float*)d_in[4];
  const float* fuse_b = (const float*)d_in[5];
  const float* fuse_g = (const float*)d_in[6];
  const float* fuse_be= (const float*)d_in[7];
  const float* e1_w   = (const float*)d_in[8];
  const float* e1_b   = (const float*)d_in[9];
  const float* e1_g   = (const float*)d_in[10];
  const float* e1_be  = (const float*)d_in[11];
  const float* e2_w   = (const float*)d_in[12];
  const float* e2_b   = (const float*)d_in[13];
  const float* e2_g   = (const float*)d_in[14];
  const float* e2_be  = (const float*)d_in[15];
  float* out = (float*)d_out;

  // workspace layout (floats)
  float* ws    = (float*)d_ws;
  float* WT1   = ws;                                   // 384*256
  float* WT2   = WT1 + 384 * 256;                      // 256*256
  float* WT3   = WT2 + 256 * 256;                      // 256*256
  float* stats = WT3 + 256 * 256;                      // 3*512
  float* ss    = stats + 3 * 512;                      // 3*512
  float* interp= ss + 3 * 512;                         // 4*256*8192
  float* bufA  = interp + (size_t)BATCH * CO * NPTS;   // 4*256*8192
  float* bufB  = bufA   + (size_t)BATCH * CO * NPTS;   // 4*256*8192

  hipMemsetAsync(stats, 0, 3 * 512 * sizeof(float), stream);

  transpose_w<<<dim3((384 * 256 + 255) / 256), 256, 0, stream>>>(fuse_w, WT1, 256, 384);
  transpose_w<<<dim3((256 * 256 + 255) / 256), 256, 0, stream>>>(e1_w, WT2, 256, 256);
  transpose_w<<<dim3((256 * 256 + 255) / 256), 256, 0, stream>>>(e2_w, WT3, 256, 256);

  knn_interp<<<dim3(NPTS / 128, BATCH), 128, 0, stream>>>(xyz1, xyz2, points2, interp);

  const int EW_BLOCKS = (BATCH * CO * NPTS) / 4 / 256; // 8192

  // stage 1: fuse  (K=384, split: points1 | interp) -> bufA; x1 -> d_out
  gemm_stats<<<dim3(NPTS / 64, 1, BATCH), 256, 0, stream>>>(
      WT1, points1, interp, fuse_b, bufA, stats, 384, 128);
  finalize_bn<<<1, 256, 0, stream>>>(stats, fuse_g, fuse_be, ss);
  bn_act<<<dim3(EW_BLOCKS), 256, 0, stream>>>(bufA, ss, out, 1);

  // stage 2: net1 -> bufB; y1 in-place
  gemm_stats<<<dim3(NPTS / 64, 1, BATCH), 256, 0, stream>>>(
      WT2, out, out, e1_b, bufB, stats + 512, 256, 256);
  finalize_bn<<<1, 256, 0, stream>>>(stats + 512, e1_g, e1_be, ss + 512);
  bn_act<<<dim3(EW_BLOCKS), 256, 0, stream>>>(bufB, ss + 512, bufB, 1);

  // stage 3: net2 -> bufA; then BN + residual(x1 in d_out) + ReLU -> d_out
  gemm_stats<<<dim3(NPTS / 64, 1, BATCH), 256, 0, stream>>>(
      WT3, bufB, bufB, e2_b, bufA, stats + 1024, 256, 256);
  finalize_bn<<<1, 256, 0, stream>>>(stats + 1024, e2_g, e2_be, ss + 1024);
  bn_res<<<dim3(EW_BLOCKS), 256, 0, stream>>>(bufA, ss + 1024, out);
}

// Round 2
// 361.455 us; speedup vs baseline: 1.9488x; 1.9488x over previous
//
#include <hip/hip_runtime.h>

#define NPTS 8192
#define SPTS 2048
#define BATCH 4
#define CO 256
#define TOTAL_ROWS (BATCH * NPTS)  // 32768

typedef __attribute__((ext_vector_type(4))) float f32x4;
typedef __attribute__((ext_vector_type(8))) short bf16x8s;
typedef __attribute__((ext_vector_type(4))) unsigned short u16x4;
typedef __attribute__((ext_vector_type(8))) unsigned short u16x8;

__device__ __forceinline__ unsigned short f2bf(float f) {
  unsigned int u = __float_as_uint(f);
  u += 0x7FFFu + ((u >> 16) & 1u);   // RNE
  return (unsigned short)(u >> 16);
}
__device__ __forceinline__ float bf2f(unsigned short h) {
  return __uint_as_float(((unsigned int)h) << 16);
}

// ---------------- convert the three weight matrices to bf16 [o][k] ----------------
__global__ __launch_bounds__(256) void cvt_w3(
    const float* __restrict__ w1, const float* __restrict__ w2,
    const float* __restrict__ w3, unsigned short* __restrict__ o1,
    unsigned short* __restrict__ o2, unsigned short* __restrict__ o3) {
  int idx = blockIdx.x * 256 + threadIdx.x;
  if (idx < 98304) o1[idx] = f2bf(w1[idx]);
  else if (idx < 163840) o2[idx - 98304] = f2bf(w2[idx - 98304]);
  else if (idx < 229376) o3[idx - 163840] = f2bf(w3[idx - 163840]);
}

// ---------------- tiled transpose: f32 [C][S] -> bf16 [S][ostride] ----------------
__global__ __launch_bounds__(256) void transpose_cb(
    const float* __restrict__ in, unsigned short* __restrict__ out,
    int C, int S, int ostride) {
  __shared__ float LT[64][65];
  const int b = blockIdx.z;
  const int s0 = blockIdx.x * 64, c0 = blockIdx.y * 64;
  const float* inb = in + (size_t)b * C * S;
  unsigned short* outb = out + (size_t)b * S * ostride;
  const int t = threadIdx.x;
  const int cr = t >> 4, sq = t & 15;
  #pragma unroll
  for (int it = 0; it < 4; ++it) {
    int cc = cr + it * 16;
    float4 v = *reinterpret_cast<const float4*>(inb + (size_t)(c0 + cc) * S + s0 + sq * 4);
    LT[sq * 4 + 0][cc] = v.x; LT[sq * 4 + 1][cc] = v.y;
    LT[sq * 4 + 2][cc] = v.z; LT[sq * 4 + 3][cc] = v.w;
  }
  __syncthreads();
  const int sr = t >> 2, cq = t & 3;
  unsigned short* op = outb + (size_t)(s0 + sr) * ostride + c0 + cq * 16;
  u16x8 o0, o1;
  #pragma unroll
  for (int k = 0; k < 8; ++k) o0[k] = f2bf(LT[sr][cq * 16 + k]);
  #pragma unroll
  for (int k = 0; k < 8; ++k) o1[k] = f2bf(LT[sr][cq * 16 + 8 + k]);
  *reinterpret_cast<u16x8*>(op) = o0;
  *reinterpret_cast<u16x8*>(op + 8) = o1;
}

// ---------------- wave-parallel KNN (k=3) ----------------
#define LT3(da, ia, db, ib) ((da) < (db) || ((da) == (db) && (ia) < (ib)))
#define INS3(dd, ii)                                                       \
  do {                                                                     \
    if (LT3(dd, ii, d2, i2)) {                                             \
      if (LT3(dd, ii, d1, i1)) {                                           \
        d2 = d1; i2 = i1;                                                  \
        if (LT3(dd, ii, d0, i0)) { d1 = d0; i1 = i0; d0 = dd; i0 = ii; }   \
        else { d1 = dd; i1 = ii; }                                         \
      } else { d2 = dd; i2 = ii; }                                         \
    }                                                                      \
  } while (0)

__global__ __launch_bounds__(256) void knn_topk(
    const float* __restrict__ xyz1, const float* __restrict__ xyz2,
    int4* __restrict__ ibuf, float4* __restrict__ wbuf) {
  __shared__ float4 spt[SPTS];
  const int b = blockIdx.y, t = threadIdx.x;
  #pragma unroll
  for (int i = 0; i < SPTS / 256; ++i) {
    int s = t + i * 256;
    const float* p = xyz2 + ((size_t)b * SPTS + s) * 3;
    float x = p[0], y = p[1], z = p[2];
    float b2 = __fadd_rn(__fadd_rn(__fmul_rn(x, x), __fmul_rn(y, y)), __fmul_rn(z, z));
    spt[s] = make_float4(x, y, z, b2);
  }
  __syncthreads();
  const int wave = t >> 6, lane = t & 63;
  for (int q = 0; q < 4; ++q) {
    int n = blockIdx.x * 16 + wave * 4 + q;
    const float* qp = xyz1 + ((size_t)b * NPTS + n) * 3;
    float qx = qp[0], qy = qp[1], qz = qp[2];
    float a2 = __fadd_rn(__fadd_rn(__fmul_rn(qx, qx), __fmul_rn(qy, qy)), __fmul_rn(qz, qz));
    float d0 = 1e30f, d1 = 1e30f, d2 = 1e30f;
    int i0 = 0, i1 = 0, i2 = 0;
    #pragma unroll 4
    for (int i = 0; i < SPTS / 64; ++i) {
      int s = i * 64 + lane;
      float4 p = spt[s];
      float dot = __fadd_rn(__fadd_rn(__fmul_rn(qx, p.x), __fmul_rn(qy, p.y)), __fmul_rn(qz, p.z));
      float d = __fsub_rn(__fadd_rn(a2, p.w), __fmul_rn(2.0f, dot));
      // ascending s => strict < keeps lowest index on ties
      if (d < d2) {
        if (d < d1) {
          d2 = d1; i2 = i1;
          if (d < d0) { d1 = d0; i1 = i0; d0 = d; i0 = s; }
          else { d1 = d; i1 = s; }
        } else { d2 = d; i2 = s; }
      }
    }
    // butterfly merge across 64 lanes, (d, idx)-lex order
    #pragma unroll
    for (int m = 1; m < 64; m <<= 1) {
      float f0 = __shfl_xor(d0, m), f1 = __shfl_xor(d1, m), f2 = __shfl_xor(d2, m);
      int j0 = __shfl_xor(i0, m), j1 = __shfl_xor(i1, m), j2 = __shfl_xor(i2, m);
      INS3(f0, j0); INS3(f1, j1); INS3(f2, j2);
    }
    if (lane == 0) {
      float r0 = 1.0f / __fadd_rn(d0, 1e-8f);
      float r1 = 1.0f / __fadd_rn(d1, 1e-8f);
      float r2 = 1.0f / __fadd_rn(d2, 1e-8f);
      float rs = __fadd_rn(__fadd_rn(r0, r1), r2);
      ibuf[(size_t)b * NPTS + n] = make_int4(i0, i1, i2, 0);
      wbuf[(size_t)b * NPTS + n] = make_float4(r0 / rs, r1 / rs, r2 / rs, 0.f);
    }
  }
}

// ---------------- IDW gather: X1[n][128+c] = sum_i w_i * p2t[idx_i][c] ----------------
__global__ __launch_bounds__(256) void interp_gather(
    const unsigned short* __restrict__ p2t, const int4* __restrict__ ibuf,
    const float4* __restrict__ wbuf, unsigned short* __restrict__ X1) {
  const int b = blockIdx.y, t = threadIdx.x;
  const int n = blockIdx.x * 64 + (t >> 2), cq = t & 3;
  int4 ii = ibuf[(size_t)b * NPTS + n];
  float4 ww = wbuf[(size_t)b * NPTS + n];
  const unsigned short* r0 = p2t + ((size_t)b * SPTS + ii.x) * 256;
  const unsigned short* r1 = p2t + ((size_t)b * SPTS + ii.y) * 256;
  const unsigned short* r2 = p2t + ((size_t)b * SPTS + ii.z) * 256;
  unsigned short* orow = X1 + ((size_t)b * NPTS + n) * 384 + 128 + cq * 64;
  #pragma unroll
  for (int j = 0; j < 8; ++j) {
    int c = cq * 64 + j * 8;
    u16x8 v0 = *reinterpret_cast<const u16x8*>(r0 + c);
    u16x8 v1 = *reinterpret_cast<const u16x8*>(r1 + c);
    u16x8 v2 = *reinterpret_cast<const u16x8*>(r2 + c);
    u16x8 o;
    #pragma unroll
    for (int e = 0; e < 8; ++e) {
      float f = ww.x * bf2f(v0[e]) + ww.y * bf2f(v1[e]) + ww.z * bf2f(v2[e]);
      o[e] = f2bf(f);
    }
    *reinterpret_cast<u16x8*>(orow + j * 8) = o;
  }
}

// ---------------- bf16 MFMA GEMM (m97-style 128x128 tile, K-step 32) ----------------
// Z[b,n,o] = sum_k Wb[o][k] * Xb[b,n,k] + bias[o]   (Z written [n][o]-major, fp32)
__global__ __launch_bounds__(256) void gemm_bf16(
    const unsigned short* __restrict__ Wb, const unsigned short* __restrict__ Xb,
    const float* __restrict__ bias, float* __restrict__ Z, int K) {
  __shared__ unsigned short As[128 * 32];
  __shared__ unsigned short Bs[128 * 32];
  const int t = threadIdx.x;
  const int o0 = blockIdx.y * 128, n0 = blockIdx.x * 128;
  const int wave = t >> 6, lane = t & 63;
  const int wo = (wave >> 1) * 64, wn = (wave & 1) * 64;
  const int lr = lane & 15, lk = (lane >> 4) * 8;
  const unsigned short* Wbase = Wb + (size_t)o0 * K;
  const unsigned short* Xbase = Xb + ((size_t)blockIdx.z * NPTS + n0) * K;

  f32x4 acc[4][4];
  #pragma unroll
  for (int i = 0; i < 4; ++i)
    #pragma unroll
    for (int j = 0; j < 4; ++j) acc[i][j] = (f32x4)0.f;

  for (int k0 = 0; k0 < K; k0 += 32) {
    #pragma unroll
    for (int i = 0; i < 2; ++i) {
      int e = t + i * 256;
      int row = e >> 2, slot = e & 3;
      *reinterpret_cast<u16x8*>(As + e * 8) =
          *reinterpret_cast<const u16x8*>(Wbase + (size_t)row * K + k0 + slot * 8);
      *reinterpret_cast<u16x8*>(Bs + e * 8) =
          *reinterpret_cast<const u16x8*>(Xbase + (size_t)row * K + k0 + slot * 8);
    }
    __syncthreads();
    bf16x8s a[4], bb[4];
    #pragma unroll
    for (int i = 0; i < 4; ++i)
      a[i] = *reinterpret_cast<const bf16x8s*>(As + (wo + i * 16 + lr) * 32 + lk);
    #pragma unroll
    for (int j = 0; j < 4; ++j)
      bb[j] = *reinterpret_cast<const bf16x8s*>(Bs + (wn + j * 16 + lr) * 32 + lk);
    #pragma unroll
    for (int i = 0; i < 4; ++i)
      #pragma unroll
      for (int j = 0; j < 4; ++j)
        acc[i][j] = __builtin_amdgcn_mfma_f32_16x16x32_bf16(a[i], bb[j], acc[i][j], 0, 0, 0);
    __syncthreads();
  }

  #pragma unroll
  for (int i = 0; i < 4; ++i) {
    int ob = o0 + wo + i * 16 + (lane >> 4) * 4;
    f32x4 bv = *reinterpret_cast<const f32x4*>(bias + ob);
    #pragma unroll
    for (int j = 0; j < 4; ++j) {
      int n = n0 + wn + j * 16 + lr;
      f32x4 v = acc[i][j] + bv;
      *reinterpret_cast<f32x4*>(Z + ((size_t)blockIdx.z * NPTS + n) * 256 + ob) = v;
    }
  }
}

// ---------------- per-channel sum / sumsq over Z [rows][256] ----------------
__global__ __launch_bounds__(256) void stats_pass(const float* __restrict__ Z,
                                                  float* __restrict__ stats) {
  __shared__ float red[4][512];
  const int t = threadIdx.x, c4 = t & 63, rq = t >> 6;
  const size_t row0 = (size_t)blockIdx.x * 64;
  float s0 = 0, s1 = 0, s2 = 0, s3 = 0, q0 = 0, q1 = 0, q2 = 0, q3 = 0;
  for (int r = rq; r < 64; r += 4) {
    float4 v = *reinterpret_cast<const float4*>(Z + (row0 + r) * 256 + c4 * 4);
    s0 += v.x; q0 += v.x * v.x; s1 += v.y; q1 += v.y * v.y;
    s2 += v.z; q2 += v.z * v.z; s3 += v.w; q3 += v.w * v.w;
  }
  float* rr = &red[rq][c4 * 8];
  rr[0] = s0; rr[1] = s1; rr[2] = s2; rr[3] = s3;
  rr[4] = q0; rr[5] = q1; rr[6] = q2; rr[7] = q3;
  __syncthreads();
  if (rq == 0) {
    #pragma unroll
    for (int k = 1; k < 4; ++k) {
      const float* pr = &red[k][c4 * 8];
      s0 += pr[0]; s1 += pr[1]; s2 += pr[2]; s3 += pr[3];
      q0 += pr[4]; q1 += pr[5]; q2 += pr[6]; q3 += pr[7];
    }
    atomicAdd(&stats[c4 * 4 + 0], s0); atomicAdd(&stats[c4 * 4 + 1], s1);
    atomicAdd(&stats[c4 * 4 + 2], s2); atomicAdd(&stats[c4 * 4 + 3], s3);
    atomicAdd(&stats[256 + c4 * 4 + 0], q0); atomicAdd(&stats[256 + c4 * 4 + 1], q1);
    atomicAdd(&stats[256 + c4 * 4 + 2], q2); atomicAdd(&stats[256 + c4 * 4 + 3], q3);
  }
}

// ---------------- BN + ReLU, f32 [rows][256] -> bf16 [rows][256] ----------------
__global__ __launch_bounds__(256) void bn_pass(
    const float* __restrict__ Z, const float* __restrict__ st,
    const float* __restrict__ gamma, const float* __restrict__ beta,
    unsigned short* __restrict__ X) {
  const int idx = blockIdx.x * 256 + threadIdx.x;
  const int c4 = idx & 63;
  const size_t row = (size_t)(idx >> 6);
  const float inv = 1.0f / (float)TOTAL_ROWS;
  float sc[4], sh[4];
  #pragma unroll
  for (int j = 0; j < 4; ++j) {
    int c = c4 * 4 + j;
    float mean = st[c] * inv;
    float var = st[256 + c] * inv - mean * mean;
    sc[j] = gamma[c] * rsqrtf(var + 1e-5f);
    sh[j] = beta[c] - mean * sc[j];
  }
  float4 z = *reinterpret_cast<const float4*>(Z + row * 256 + c4 * 4);
  u16x4 o;
  o[0] = f2bf(fmaxf(sc[0] * z.x + sh[0], 0.f));
  o[1] = f2bf(fmaxf(sc[1] * z.y + sh[1], 0.f));
  o[2] = f2bf(fmaxf(sc[2] * z.z + sh[2], 0.f));
  o[3] = f2bf(fmaxf(sc[3] * z.w + sh[3], 0.f));
  *reinterpret_cast<u16x4*>(X + row * 256 + c4 * 4) = o;
}

// ---------------- final: BN + residual + ReLU + transpose to out[b][o][n] ----------------
__global__ __launch_bounds__(256) void bn_res_out(
    const float* __restrict__ Z, const unsigned short* __restrict__ Xact,
    const float* __restrict__ st, const float* __restrict__ gamma,
    const float* __restrict__ beta, float* __restrict__ out) {
  __shared__ float LT[64][68];
  const int b = blockIdx.z, n0 = blockIdx.x * 64, o0 = blockIdx.y * 64;
  const int t = threadIdx.x;
  const int nr = t >> 4, oq = t & 15;
  const float inv = 1.0f / (float)TOTAL_ROWS;
  float sc[4], sh[4];
  #pragma unroll
  for (int j = 0; j < 4; ++j) {
    int c = o0 + oq * 4 + j;
    float mean = st[c] * inv;
    float var = st[256 + c] * inv - mean * mean;
    sc[j] = gamma[c] * rsqrtf(var + 1e-5f);
    sh[j] = beta[c] - mean * sc[j];
  }
  #pragma unroll
  for (int it = 0; it < 4; ++it) {
    int nn = nr + it * 16;
    size_t row = (size_t)b * NPTS + n0 + nn;
    float4 z = *reinterpret_cast<const float4*>(Z + row * 256 + o0 + oq * 4);
    u16x4 x = *reinterpret_cast<const u16x4*>(Xact + row * 256 + o0 + oq * 4);
    f32x4 y;
    y[0] = fmaxf(sc[0] * z.x + sh[0] + bf2f(x[0]), 0.f);
    y[1] = fmaxf(sc[1] * z.y + sh[1] + bf2f(x[1]), 0.f);
    y[2] = fmaxf(sc[2] * z.z + sh[2] + bf2f(x[2]), 0.f);
    y[3] = fmaxf(sc[3] * z.w + sh[3] + bf2f(x[3]), 0.f);
    *reinterpret_cast<f32x4*>(&LT[nn][oq * 4]) = y;
  }
  __syncthreads();
  const int orow = t >> 2, nq = t & 3;
  float* op = out + ((size_t)b * CO + o0 + orow) * NPTS + n0 + nq * 16;
  #pragma unroll
  for (int j = 0; j < 4; ++j) {
    float4 v = make_float4(LT[nq * 16 + j * 4 + 0][orow], LT[nq * 16 + j * 4 + 1][orow],
                           LT[nq * 16 + j * 4 + 2][orow], LT[nq * 16 + j * 4 + 3][orow]);
    *reinterpret_cast<float4*>(op + j * 4) = v;
  }
}

extern "C" void kernel_launch(void* const* d_in, const int* in_sizes, int n_in,
                              void* d_out, int out_size, void* d_ws, size_t ws_size,
                              hipStream_t stream) {
  const float* xyz1    = (const float*)d_in[0];
  const float* xyz2    = (const float*)d_in[1];
  const float* points1 = (const float*)d_in[2];
  const float* points2 = (const float*)d_in[3];
  const float* fuse_w  = (const float*)d_in[4];
  const float* fuse_b  = (const float*)d_in[5];
  const float* fuse_g  = (const float*)d_in[6];
  const float* fuse_be = (const float*)d_in[7];
  const float* e1_w    = (const float*)d_in[8];
  const float* e1_b    = (const float*)d_in[9];
  const float* e1_g    = (const float*)d_in[10];
  const float* e1_be   = (const float*)d_in[11];
  const float* e2_w    = (const float*)d_in[12];
  const float* e2_b    = (const float*)d_in[13];
  const float* e2_g    = (const float*)d_in[14];
  const float* e2_be   = (const float*)d_in[15];
  float* out = (float*)d_out;

  // workspace carve-up (256B aligned)
  char* w = (char*)d_ws;
  auto carve = [&](size_t bytes) {
    char* p = w;
    w += (bytes + 255) & ~(size_t)255;
    return p;
  };
  unsigned short* Wb1 = (unsigned short*)carve(98304 * 2);
  unsigned short* Wb2 = (unsigned short*)carve(65536 * 2);
  unsigned short* Wb3 = (unsigned short*)carve(65536 * 2);
  unsigned short* p2t = (unsigned short*)carve((size_t)BATCH * SPTS * 256 * 2);
  int4* ibuf          = (int4*)carve((size_t)BATCH * NPTS * 16);
  float4* wbuf        = (float4*)carve((size_t)BATCH * NPTS * 16);
  unsigned short* X1  = (unsigned short*)carve((size_t)BATCH * NPTS * 384 * 2);
  unsigned short* Xact= (unsigned short*)carve((size_t)BATCH * NPTS * 256 * 2);
  unsigned short* X3  = (unsigned short*)carve((size_t)BATCH * NPTS * 256 * 2);
  float* Z            = (float*)carve((size_t)BATCH * NPTS * 256 * 4);
  float* stats        = (float*)carve(3 * 512 * 4);

  hipMemsetAsync(stats, 0, 3 * 512 * sizeof(float), stream);

  cvt_w3<<<dim3(896), 256, 0, stream>>>(fuse_w, e1_w, e2_w, Wb1, Wb2, Wb3);
  // points2 [256][2048] -> p2t bf16 [2048][256]
  transpose_cb<<<dim3(32, 4, BATCH), 256, 0, stream>>>(points2, p2t, 256, SPTS, 256);
  // points1 [128][8192] -> X1[:, 0:128] bf16 (row stride 384)
  transpose_cb<<<dim3(128, 2, BATCH), 256, 0, stream>>>(points1, X1, 128, NPTS, 384);

  knn_topk<<<dim3(NPTS / 16, BATCH), 256, 0, stream>>>(xyz1, xyz2, ibuf, wbuf);
  interp_gather<<<dim3(NPTS / 64, BATCH), 256, 0, stream>>>(p2t, ibuf, wbuf, X1);

  const dim3 ggrid(NPTS / 128, 2, BATCH);
  const int STAT_BLOCKS = TOTAL_ROWS / 64;       // 512
  const int BN_BLOCKS = TOTAL_ROWS * 64 / 256;   // 8192

  // stage 1: fuse (K=384)
  gemm_bf16<<<ggrid, 256, 0, stream>>>(Wb1, X1, fuse_b, Z, 384);
  stats_pass<<<dim3(STAT_BLOCKS), 256, 0, stream>>>(Z, stats);
  bn_pass<<<dim3(BN_BLOCKS), 256, 0, stream>>>(Z, stats, fuse_g, fuse_be, Xact);

  // stage 2: net1 (K=256)
  gemm_bf16<<<ggrid, 256, 0, stream>>>(Wb2, Xact, e1_b, Z, 256);
  stats_pass<<<dim3(STAT_BLOCKS), 256, 0, stream>>>(Z, stats + 512);
  bn_pass<<<dim3(BN_BLOCKS), 256, 0, stream>>>(Z, stats + 512, e1_g, e1_be, X3);

  // stage 3: net2 (K=256) + BN + residual(Xact) + ReLU + transpose out
  gemm_bf16<<<ggrid, 256, 0, stream>>>(Wb3, X3, e2_b, Z, 256);
  stats_pass<<<dim3(STAT_BLOCKS), 256, 0, stream>>>(Z, stats + 1024);
  bn_res_out<<<dim3(NPTS / 64, 4, BATCH), 256, 0, stream>>>(Z, Xact, stats + 1024,
                                                            e2_g, e2_be, out);
}

// Round 3
// 339.941 us; speedup vs baseline: 2.0721x; 1.0633x over previous
//
#include <hip/hip_runtime.h>

#define NPTS 8192
#define SPTS 2048
#define BATCH 4
#define CO 256
#define TOTAL_ROWS (BATCH * NPTS)  // 32768

typedef __attribute__((ext_vector_type(4))) float f32x4;
typedef __attribute__((ext_vector_type(8))) short bf16x8s;
typedef __attribute__((ext_vector_type(4))) unsigned short u16x4;
typedef __attribute__((ext_vector_type(8))) unsigned short u16x8;

__device__ __forceinline__ unsigned short f2bf(float f) {
  unsigned int u = __float_as_uint(f);
  u += 0x7FFFu + ((u >> 16) & 1u);   // RNE
  return (unsigned short)(u >> 16);
}
__device__ __forceinline__ float bf2f(unsigned short h) {
  return __uint_as_float(((unsigned int)h) << 16);
}

__device__ __forceinline__ void gload_lds16(const void* g, void* l) {
  __builtin_amdgcn_global_load_lds((const __attribute__((address_space(1))) void*)g,
                                   (__attribute__((address_space(3))) void*)l, 16, 0, 0);
}

// ---------------- convert the three weight matrices to bf16 [o][k] ----------------
__global__ __launch_bounds__(256) void cvt_w3(
    const float* __restrict__ w1, const float* __restrict__ w2,
    const float* __restrict__ w3, unsigned short* __restrict__ o1,
    unsigned short* __restrict__ o2, unsigned short* __restrict__ o3) {
  int idx = blockIdx.x * 256 + threadIdx.x;
  if (idx < 98304) o1[idx] = f2bf(w1[idx]);
  else if (idx < 163840) o2[idx - 98304] = f2bf(w2[idx - 98304]);
  else if (idx < 229376) o3[idx - 163840] = f2bf(w3[idx - 163840]);
}

// ---------------- tiled transpose: f32 [C][S] -> bf16 [S][ostride] ----------------
__global__ __launch_bounds__(256) void transpose_cb(
    const float* __restrict__ in, unsigned short* __restrict__ out,
    int C, int S, int ostride) {
  __shared__ float LT[64][65];
  const int b = blockIdx.z;
  const int s0 = blockIdx.x * 64, c0 = blockIdx.y * 64;
  const float* inb = in + (size_t)b * C * S;
  unsigned short* outb = out + (size_t)b * S * ostride;
  const int t = threadIdx.x;
  const int cr = t >> 4, sq = t & 15;
  #pragma unroll
  for (int it = 0; it < 4; ++it) {
    int cc = cr + it * 16;
    float4 v = *reinterpret_cast<const float4*>(inb + (size_t)(c0 + cc) * S + s0 + sq * 4);
    LT[sq * 4 + 0][cc] = v.x; LT[sq * 4 + 1][cc] = v.y;
    LT[sq * 4 + 2][cc] = v.z; LT[sq * 4 + 3][cc] = v.w;
  }
  __syncthreads();
  const int sr = t >> 2, cq = t & 3;
  unsigned short* op = outb + (size_t)(s0 + sr) * ostride + c0 + cq * 16;
  u16x8 o0, o1;
  #pragma unroll
  for (int k = 0; k < 8; ++k) o0[k] = f2bf(LT[sr][cq * 16 + k]);
  #pragma unroll
  for (int k = 0; k < 8; ++k) o1[k] = f2bf(LT[sr][cq * 16 + 8 + k]);
  *reinterpret_cast<u16x8*>(op) = o0;
  *reinterpret_cast<u16x8*>(op + 8) = o1;
}

// ---------------- wave-parallel KNN (k=3), 4 queries per wave per scan ----------------
#define LT3(da, ia, db, ib) ((da) < (db) || ((da) == (db) && (ia) < (ib)))
#define INS3(dd, ii)                                                       \
  do {                                                                     \
    if (LT3(dd, ii, m2, j2)) {                                             \
      if (LT3(dd, ii, m1, j1)) {                                           \
        m2 = m1; j2 = j1;                                                  \
        if (LT3(dd, ii, m0, j0)) { m1 = m0; j1 = j0; m0 = dd; j0 = ii; }   \
        else { m1 = dd; j1 = ii; }                                         \
      } else { m2 = dd; j2 = ii; }                                         \
    }                                                                      \
  } while (0)

__global__ __launch_bounds__(256) void knn_topk(
    const float* __restrict__ xyz1, const float* __restrict__ xyz2,
    int4* __restrict__ ibuf, float4* __restrict__ wbuf) {
  __shared__ float4 spt[SPTS];
  const int b = blockIdx.y, t = threadIdx.x;
  #pragma unroll
  for (int i = 0; i < SPTS / 256; ++i) {
    int s = t + i * 256;
    const float* p = xyz2 + ((size_t)b * SPTS + s) * 3;
    float x = p[0], y = p[1], z = p[2];
    float b2 = __fadd_rn(__fadd_rn(__fmul_rn(x, x), __fmul_rn(y, y)), __fmul_rn(z, z));
    spt[s] = make_float4(x, y, z, b2);
  }
  __syncthreads();
  const int wave = t >> 6, lane = t & 63;
  const int nb = blockIdx.x * 16 + wave * 4;

  float qx[4], qy[4], qz[4], a2[4];
  float d0[4], d1[4], d2[4];
  int i0[4], i1[4], i2[4];
  #pragma unroll
  for (int q = 0; q < 4; ++q) {
    const float* qp = xyz1 + ((size_t)b * NPTS + nb + q) * 3;
    qx[q] = qp[0]; qy[q] = qp[1]; qz[q] = qp[2];
    a2[q] = __fadd_rn(__fadd_rn(__fmul_rn(qx[q], qx[q]), __fmul_rn(qy[q], qy[q])),
                      __fmul_rn(qz[q], qz[q]));
    d0[q] = 1e30f; d1[q] = 1e30f; d2[q] = 1e30f;
    i0[q] = 0; i1[q] = 0; i2[q] = 0;
  }

  #pragma unroll 2
  for (int it = 0; it < SPTS / 64; ++it) {
    int s = it * 64 + lane;
    float4 p = spt[s];
    #pragma unroll
    for (int q = 0; q < 4; ++q) {
      float dot = __fadd_rn(__fadd_rn(__fmul_rn(qx[q], p.x), __fmul_rn(qy[q], p.y)),
                            __fmul_rn(qz[q], p.z));
      float d = __fsub_rn(__fadd_rn(a2[q], p.w), __fmul_rn(2.0f, dot));
      // compare-swap network insert of (d, s); strict < keeps lowest index
      float tt = d; int ti = s;
      bool c0 = tt < d0[q];
      float h = c0 ? d0[q] : tt; int hi_ = c0 ? i0[q] : ti;
      d0[q] = c0 ? tt : d0[q];   i0[q] = c0 ? ti : i0[q];
      tt = h; ti = hi_;
      bool c1 = tt < d1[q];
      h = c1 ? d1[q] : tt; hi_ = c1 ? i1[q] : ti;
      d1[q] = c1 ? tt : d1[q];   i1[q] = c1 ? ti : i1[q];
      tt = h; ti = hi_;
      bool c2 = tt < d2[q];
      d2[q] = c2 ? tt : d2[q];   i2[q] = c2 ? ti : i2[q];
    }
  }

  #pragma unroll
  for (int q = 0; q < 4; ++q) {
    float m0 = d0[q], m1 = d1[q], m2 = d2[q];
    int j0 = i0[q], j1 = i1[q], j2 = i2[q];
    // butterfly merge across 64 lanes, (d, idx)-lex order
    #pragma unroll
    for (int m = 1; m < 64; m <<= 1) {
      float f0 = __shfl_xor(m0, m), f1 = __shfl_xor(m1, m), f2 = __shfl_xor(m2, m);
      int g0 = __shfl_xor(j0, m), g1 = __shfl_xor(j1, m), g2 = __shfl_xor(j2, m);
      INS3(f0, g0); INS3(f1, g1); INS3(f2, g2);
    }
    if (lane == 0) {
      float r0 = 1.0f / __fadd_rn(m0, 1e-8f);
      float r1 = 1.0f / __fadd_rn(m1, 1e-8f);
      float r2 = 1.0f / __fadd_rn(m2, 1e-8f);
      float rs = __fadd_rn(__fadd_rn(r0, r1), r2);
      ibuf[(size_t)b * NPTS + nb + q] = make_int4(j0, j1, j2, 0);
      wbuf[(size_t)b * NPTS + nb + q] = make_float4(r0 / rs, r1 / rs, r2 / rs, 0.f);
    }
  }
}

// ---------------- IDW gather: X1[n][128+c] = sum_i w_i * p2t[idx_i][c] ----------------
__global__ __launch_bounds__(256) void interp_gather(
    const unsigned short* __restrict__ p2t, const int4* __restrict__ ibuf,
    const float4* __restrict__ wbuf, unsigned short* __restrict__ X1) {
  const int b = blockIdx.y, t = threadIdx.x;
  const int n = blockIdx.x * 64 + (t >> 2), cq = t & 3;
  int4 ii = ibuf[(size_t)b * NPTS + n];
  float4 ww = wbuf[(size_t)b * NPTS + n];
  const unsigned short* r0 = p2t + ((size_t)b * SPTS + ii.x) * 256;
  const unsigned short* r1 = p2t + ((size_t)b * SPTS + ii.y) * 256;
  const unsigned short* r2 = p2t + ((size_t)b * SPTS + ii.z) * 256;
  unsigned short* orow = X1 + ((size_t)b * NPTS + n) * 384 + 128 + cq * 64;
  #pragma unroll
  for (int j = 0; j < 8; ++j) {
    int c = cq * 64 + j * 8;
    u16x8 v0 = *reinterpret_cast<const u16x8*>(r0 + c);
    u16x8 v1 = *reinterpret_cast<const u16x8*>(r1 + c);
    u16x8 v2 = *reinterpret_cast<const u16x8*>(r2 + c);
    u16x8 o;
    #pragma unroll
    for (int e = 0; e < 8; ++e) {
      float f = ww.x * bf2f(v0[e]) + ww.y * bf2f(v1[e]) + ww.z * bf2f(v2[e]);
      o[e] = f2bf(f);
    }
    *reinterpret_cast<u16x8*>(orow + j * 8) = o;
  }
}

// ---------------- bf16 MFMA GEMM, global_load_lds staging, fused BN stats ----------------
// Z[b,n,o] = sum_k Wb[o][k] * Xb[b,n,k] + bias[o]; Z stored bf16 [n][256].
// stats[0:256] += per-channel sum, stats[256:512] += per-channel sumsq.
__global__ __launch_bounds__(256) void gemm_bf16(
    const unsigned short* __restrict__ Wb, const unsigned short* __restrict__ Xb,
    const float* __restrict__ bias, unsigned short* __restrict__ Z,
    float* __restrict__ stats, int K) {
  __shared__ unsigned short As[128 * 32];
  __shared__ unsigned short Bs[128 * 32];
  const int t = threadIdx.x;
  const int o0 = blockIdx.y * 128, n0 = blockIdx.x * 128;
  const int wave = t >> 6, lane = t & 63;
  const int wo = (wave >> 1) * 64, wn = (wave & 1) * 64;
  const int lr = lane & 15, hi = lane >> 4;
  const unsigned short* Wbase = Wb + (size_t)o0 * K;
  const unsigned short* Xbase = Xb + ((size_t)blockIdx.z * NPTS + n0) * K;
  const int srow = t >> 2, sslot = t & 3;

  f32x4 acc[4][4];
  #pragma unroll
  for (int i = 0; i < 4; ++i)
    #pragma unroll
    for (int j = 0; j < 4; ++j) acc[i][j] = (f32x4)0.f;

  for (int k0 = 0; k0 < K; k0 += 32) {
    gload_lds16(Wbase + (size_t)srow * K + k0 + sslot * 8, As + t * 8);
    gload_lds16(Wbase + (size_t)(srow + 64) * K + k0 + sslot * 8, As + (t + 256) * 8);
    gload_lds16(Xbase + (size_t)srow * K + k0 + sslot * 8, Bs + t * 8);
    gload_lds16(Xbase + (size_t)(srow + 64) * K + k0 + sslot * 8, Bs + (t + 256) * 8);
    __syncthreads();
    bf16x8s a[4], bb[4];
    #pragma unroll
    for (int i = 0; i < 4; ++i)
      a[i] = *reinterpret_cast<const bf16x8s*>(As + (wo + i * 16 + lr) * 32 + hi * 8);
    #pragma unroll
    for (int j = 0; j < 4; ++j)
      bb[j] = *reinterpret_cast<const bf16x8s*>(Bs + (wn + j * 16 + lr) * 32 + hi * 8);
    #pragma unroll
    for (int i = 0; i < 4; ++i)
      #pragma unroll
      for (int j = 0; j < 4; ++j)
        acc[i][j] = __builtin_amdgcn_mfma_f32_16x16x32_bf16(a[i], bb[j], acc[i][j], 0, 0, 0);
    __syncthreads();
  }

  #pragma unroll
  for (int i = 0; i < 4; ++i) {
    int ob = o0 + wo + i * 16 + hi * 4;
    f32x4 bv = *reinterpret_cast<const f32x4*>(bias + ob);
    f32x4 vv[4];
    #pragma unroll
    for (int j = 0; j < 4; ++j) {
      vv[j] = acc[i][j] + bv;
      int n = n0 + wn + j * 16 + lr;
      u16x4 o;
      #pragma unroll
      for (int e = 0; e < 4; ++e) o[e] = f2bf(vv[j][e]);
      *reinterpret_cast<u16x4*>(Z + ((size_t)blockIdx.z * NPTS + n) * 256 + ob) = o;
    }
    float s[4], q[4];
    #pragma unroll
    for (int e = 0; e < 4; ++e) {
      float a0 = vv[0][e], a1 = vv[1][e], a2_ = vv[2][e], a3 = vv[3][e];
      s[e] = (a0 + a1) + (a2_ + a3);
      q[e] = (a0 * a0 + a1 * a1) + (a2_ * a2_ + a3 * a3);
    }
    #pragma unroll
    for (int m = 8; m >= 1; m >>= 1) {
      #pragma unroll
      for (int e = 0; e < 4; ++e) {
        s[e] += __shfl_xor(s[e], m);
        q[e] += __shfl_xor(q[e], m);
      }
    }
    if (lr == 0) {
      #pragma unroll
      for (int e = 0; e < 4; ++e) {
        atomicAdd(stats + ob + e, s[e]);
        atomicAdd(stats + 256 + ob + e, q[e]);
      }
    }
  }
}

// ---------------- BN + ReLU: bf16 Z [rows][256] -> bf16 X [rows][256] ----------------
__global__ __launch_bounds__(256) void bn_pass(
    const unsigned short* __restrict__ Z, const float* __restrict__ st,
    const float* __restrict__ gamma, const float* __restrict__ beta,
    unsigned short* __restrict__ X) {
  const int t = threadIdx.x;
  const size_t base = (size_t)blockIdx.x * 2048 + t * 8;  // 8 rows/block
  const int col = (t & 31) * 8;
  const float inv = 1.0f / (float)TOTAL_ROWS;
  float sc[8], sh[8];
  #pragma unroll
  for (int e = 0; e < 8; ++e) {
    int c = col + e;
    float mean = st[c] * inv;
    float var = st[256 + c] * inv - mean * mean;
    sc[e] = gamma[c] * rsqrtf(var + 1e-5f);
    sh[e] = beta[c] - mean * sc[e];
  }
  u16x8 z = *reinterpret_cast<const u16x8*>(Z + base);
  u16x8 o;
  #pragma unroll
  for (int e = 0; e < 8; ++e)
    o[e] = f2bf(fmaxf(sc[e] * bf2f(z[e]) + sh[e], 0.f));
  *reinterpret_cast<u16x8*>(X + base) = o;
}

// ---------------- final: BN + residual + ReLU + transpose to out[b][o][n] ----------------
__global__ __launch_bounds__(256) void bn_res_out(
    const unsigned short* __restrict__ Z, const unsigned short* __restrict__ Xact,
    const float* __restrict__ st, const float* __restrict__ gamma,
    const float* __restrict__ beta, float* __restrict__ out) {
  __shared__ float LT[64][69];
  const int b = blockIdx.z, n0 = blockIdx.x * 64, o0 = blockIdx.y * 64;
  const int t = threadIdx.x;
  const int nr = t >> 4, oq = t & 15;
  const float inv = 1.0f / (float)TOTAL_ROWS;
  float sc[4], sh[4];
  #pragma unroll
  for (int j = 0; j < 4; ++j) {
    int c = o0 + oq * 4 + j;
    float mean = st[c] * inv;
    float var = st[256 + c] * inv - mean * mean;
    sc[j] = gamma[c] * rsqrtf(var + 1e-5f);
    sh[j] = beta[c] - mean * sc[j];
  }
  #pragma unroll
  for (int it = 0; it < 4; ++it) {
    int nn = nr + it * 16;
    size_t row = (size_t)b * NPTS + n0 + nn;
    u16x4 z = *reinterpret_cast<const u16x4*>(Z + row * 256 + o0 + oq * 4);
    u16x4 x = *reinterpret_cast<const u16x4*>(Xact + row * 256 + o0 + oq * 4);
    #pragma unroll
    for (int e = 0; e < 4; ++e)
      LT[nn][oq * 4 + e] = fmaxf(sc[e] * bf2f(z[e]) + sh[e] + bf2f(x[e]), 0.f);
  }
  __syncthreads();
  const int orow = t >> 2, nq = t & 3;
  float* op = out + ((size_t)b * CO + o0 + orow) * NPTS + n0 + nq * 16;
  #pragma unroll
  for (int j = 0; j < 4; ++j) {
    float4 v = make_float4(LT[nq * 16 + j * 4 + 0][orow], LT[nq * 16 + j * 4 + 1][orow],
                           LT[nq * 16 + j * 4 + 2][orow], LT[nq * 16 + j * 4 + 3][orow]);
    *reinterpret_cast<float4*>(op + j * 4) = v;
  }
}

extern "C" void kernel_launch(void* const* d_in, const int* in_sizes, int n_in,
                              void* d_out, int out_size, void* d_ws, size_t ws_size,
                              hipStream_t stream) {
  const float* xyz1    = (const float*)d_in[0];
  const float* xyz2    = (const float*)d_in[1];
  const float* points1 = (const float*)d_in[2];
  const float* points2 = (const float*)d_in[3];
  const float* fuse_w  = (const float*)d_in[4];
  const float* fuse_b  = (const float*)d_in[5];
  const float* fuse_g  = (const float*)d_in[6];
  const float* fuse_be = (const float*)d_in[7];
  const float* e1_w    = (const float*)d_in[8];
  const float* e1_b    = (const float*)d_in[9];
  const float* e1_g    = (const float*)d_in[10];
  const float* e1_be   = (const float*)d_in[11];
  const float* e2_w    = (const float*)d_in[12];
  const float* e2_b    = (const float*)d_in[13];
  const float* e2_g    = (const float*)d_in[14];
  const float* e2_be   = (const float*)d_in[15];
  float* out = (float*)d_out;

  char* w = (char*)d_ws;
  auto carve = [&](size_t bytes) {
    char* p = w;
    w += (bytes + 255) & ~(size_t)255;
    return p;
  };
  unsigned short* Wb1 = (unsigned short*)carve(98304 * 2);
  unsigned short* Wb2 = (unsigned short*)carve(65536 * 2);
  unsigned short* Wb3 = (unsigned short*)carve(65536 * 2);
  unsigned short* p2t = (unsigned short*)carve((size_t)BATCH * SPTS * 256 * 2);
  int4* ibuf          = (int4*)carve((size_t)BATCH * NPTS * 16);
  float4* wbuf        = (float4*)carve((size_t)BATCH * NPTS * 16);
  unsigned short* X1  = (unsigned short*)carve((size_t)BATCH * NPTS * 384 * 2);
  unsigned short* Xact= (unsigned short*)carve((size_t)BATCH * NPTS * 256 * 2);
  unsigned short* X3  = (unsigned short*)carve((size_t)BATCH * NPTS * 256 * 2);
  unsigned short* Z   = (unsigned short*)carve((size_t)BATCH * NPTS * 256 * 2);
  float* stats        = (float*)carve(3 * 512 * 4);

  hipMemsetAsync(stats, 0, 3 * 512 * sizeof(float), stream);

  cvt_w3<<<dim3(896), 256, 0, stream>>>(fuse_w, e1_w, e2_w, Wb1, Wb2, Wb3);
  transpose_cb<<<dim3(32, 4, BATCH), 256, 0, stream>>>(points2, p2t, 256, SPTS, 256);
  transpose_cb<<<dim3(128, 2, BATCH), 256, 0, stream>>>(points1, X1, 128, NPTS, 384);

  knn_topk<<<dim3(NPTS / 16, BATCH), 256, 0, stream>>>(xyz1, xyz2, ibuf, wbuf);
  interp_gather<<<dim3(NPTS / 64, BATCH), 256, 0, stream>>>(p2t, ibuf, wbuf, X1);

  const dim3 ggrid(NPTS / 128, 2, BATCH);
  const int BN_BLOCKS = TOTAL_ROWS * 256 / 2048;  // 4096

  // stage 1: fuse (K=384)
  gemm_bf16<<<ggrid, 256, 0, stream>>>(Wb1, X1, fuse_b, Z, stats, 384);
  bn_pass<<<dim3(BN_BLOCKS), 256, 0, stream>>>(Z, stats, fuse_g, fuse_be, Xact);

  // stage 2: net1 (K=256)
  gemm_bf16<<<ggrid, 256, 0, stream>>>(Wb2, Xact, e1_b, Z, stats + 512, 256);
  bn_pass<<<dim3(BN_BLOCKS), 256, 0, stream>>>(Z, stats + 512, e1_g, e1_be, X3);

  // stage 3: net2 (K=256) + BN + residual(Xact) + ReLU + transpose out
  gemm_bf16<<<ggrid, 256, 0, stream>>>(Wb3, X3, e2_b, Z, stats + 1024, 256);
  bn_res_out<<<dim3(NPTS / 64, 4, BATCH), 256, 0, stream>>>(Z, Xact, stats + 1024,
                                                            e2_g, e2_be, out);
}